// Round 13
// baseline (137.559 us; speedup 1.0000x reference)
//
#include <hip/hip_runtime.h>
#include <math.h>

#define B_ 2
#define S_ 2048
#define D_ 1024
#define H_ 16
#define HD_ 64

typedef __bf16 bf16x8 __attribute__((ext_vector_type(8)));
typedef __bf16 bf16x4 __attribute__((ext_vector_type(4)));
typedef __bf16 bf16x2 __attribute__((ext_vector_type(2)));
typedef float f32x4 __attribute__((ext_vector_type(4)));
typedef float f32x16 __attribute__((ext_vector_type(16)));
typedef unsigned u32x2 __attribute__((ext_vector_type(2)));

#define GLOAD16(gsrc, ldst) \
  __builtin_amdgcn_global_load_lds((const __attribute__((address_space(1))) void*)(gsrc), \
                                   (__attribute__((address_space(3))) void*)(ldst), 16, 0, 0)

// 0.125 (1/sqrt(hd)) * log2(e), folded into W_qkv's q columns
#define QSCALE 0.18033688f

static __device__ __forceinline__ unsigned pack2(float a, float b) {
    bf16x2 v; v[0] = (__bf16)a; v[1] = (__bf16)b;
    return __builtin_bit_cast(unsigned, v);
}

// ---------------- fused prep: conv(x) + transpose(Wqkv) + transpose(Wproj) ---
// grid 3072: [0,2048) conv, [2048,2816) Wqkv transpose, [2816,3072) Wproj.
__global__ __launch_bounds__(256) void prep_k(
    const float* __restrict__ x, __bf16* __restrict__ x_bf,
    const float* __restrict__ Wqkv, __bf16* __restrict__ wq_t,
    const float* __restrict__ Wproj, __bf16* __restrict__ wp_t)
{
    __shared__ float t[64][65];
    const int tid = threadIdx.x;
    const int bid = blockIdx.x;

    if (bid < 2048) {
        int i = (bid * 256 + tid) * 8;
        float4 a = *(const float4*)(x + i);
        float4 b = *(const float4*)(x + i + 4);
        bf16x8 v;
        v[0] = (__bf16)a.x; v[1] = (__bf16)a.y; v[2] = (__bf16)a.z; v[3] = (__bf16)a.w;
        v[4] = (__bf16)b.x; v[5] = (__bf16)b.y; v[6] = (__bf16)b.z; v[7] = (__bf16)b.w;
        *(bf16x8*)(x_bf + i) = v;
        return;
    }

    const float* in; __bf16* outp; int K, N, qcols; float qs; int bx, by;
    if (bid < 2816) {
        int tt = bid - 2048; bx = tt % 48; by = tt / 48;
        in = Wqkv; outp = wq_t; K = D_; N = 3 * D_; qcols = D_; qs = QSCALE;
    } else {
        int tt = bid - 2816; bx = tt % 16; by = tt / 16;
        in = Wproj; outp = wp_t; K = D_; N = D_; qcols = 0; qs = 1.0f;
    }
    const int bj = bx * 64;   // N dim
    const int bi = by * 64;   // K dim
    #pragma unroll
    for (int it = 0; it < 4; ++it) {
        int idx = (tid + it * 256) * 4;
        int r = idx >> 6, c = idx & 63;
        float4 v = *(const float4*)(in + (size_t)(bi + r) * N + bj + c);
        t[r][c] = v.x; t[r][c+1] = v.y; t[r][c+2] = v.z; t[r][c+3] = v.w;
    }
    __syncthreads();
    int j = tid & 63;
    int i0 = (tid >> 6) * 16;
    float s = (bj + j) < qcols ? qs : 1.0f;
    bf16x8 h0, h1;
    #pragma unroll
    for (int ii = 0; ii < 8; ++ii) h0[ii] = (__bf16)(t[i0 + ii][j] * s);
    #pragma unroll
    for (int ii = 0; ii < 8; ++ii) h1[ii] = (__bf16)(t[i0 + 8 + ii][j] * s);
    size_t o = (size_t)(bj + j) * K + bi + i0;
    *(bf16x8*)(outp + o) = h0; *(bf16x8*)(outp + o + 8) = h1;
}

// ---------------- GEMM1: C[M][N] = A[M][K] * Bt[N][K]^T + bias ---------------
__global__ __launch_bounds__(256) void gemm_nt_k(
    const __bf16* __restrict__ A, const __bf16* __restrict__ Bt,
    const float* __restrict__ bias, __bf16* __restrict__ C,
    int M, int N, int K, int qcols, float qs)
{
    constexpr int TSZ = 128 * 64;
    __shared__ __bf16 sA[TSZ];
    __shared__ __bf16 sB[TSZ];

    const int tid = threadIdx.x, w = tid >> 6, l = tid & 63;
    const int lr = l & 15, lg = l >> 4;
    const int bm = blockIdx.y * 128, bn = blockIdx.x * 128;
    const int wm = w >> 1, wn = w & 1;

    f32x4 acc[4][4] = {};

    for (int k0 = 0; k0 < K; k0 += 64) {
        __syncthreads();
        #pragma unroll
        for (int c = 0; c < 4; ++c) {
            int q = w * 4 + c;
            int r = q * 8 + (l >> 3);
            int sl = ((l & 7) ^ (r & 7)) * 8;
            GLOAD16(A + (size_t)(bm + r) * K + k0 + sl, sA + q * 512);
            GLOAD16(Bt + (size_t)(bn + r) * K + k0 + sl, sB + q * 512);
        }
        __syncthreads();
        #pragma unroll
        for (int kk = 0; kk < 2; ++kk) {
            bf16x8 ah[4], bh[4];
            #pragma unroll
            for (int i = 0; i < 4; ++i) {
                int ra = wm * 64 + i * 16 + lr;
                int sa = ((kk * 4 + lg) ^ (ra & 7)) * 8;
                ah[i] = *(const bf16x8*)(sA + ra * 64 + sa);
                int rb = wn * 64 + i * 16 + lr;
                int sb = ((kk * 4 + lg) ^ (rb & 7)) * 8;
                bh[i] = *(const bf16x8*)(sB + rb * 64 + sb);
            }
            #pragma unroll
            for (int mi = 0; mi < 4; ++mi)
                #pragma unroll
                for (int ni = 0; ni < 4; ++ni)
                    acc[mi][ni] = __builtin_amdgcn_mfma_f32_16x16x32_bf16(ah[mi], bh[ni], acc[mi][ni], 0, 0, 0);
        }
    }

    #pragma unroll
    for (int ni = 0; ni < 4; ++ni) {
        int col = bn + wn * 64 + ni * 16 + lr;
        float bv = bias[col];
        if (col < qcols) bv *= qs;
        #pragma unroll
        for (int mi = 0; mi < 4; ++mi) {
            #pragma unroll
            for (int r = 0; r < 4; ++r) {
                int row = bm + wm * 64 + mi * 16 + lg * 4 + r;
                float v = acc[mi][ni][r] + bv;
                C[(size_t)row * N + col] = (__bf16)v;
            }
        }
    }
}

// ---- GEMM2 + combine: out = ((P0+P1)/(l0+l1)) @ Wp^T + bias -> fp32 --------
// A-staging: reg-load 2 partial streams (pre-swizzled source), sum, scale by
// 1/lsum, ds_write_b128 to the same linear LDS position gload_lds would use.
__global__ __launch_bounds__(256) void gemm2_comb_k(
    const __bf16* __restrict__ P, const float* __restrict__ L,
    const __bf16* __restrict__ Bt, const float* __restrict__ bias,
    float* __restrict__ C)
{
    constexpr int K = D_, N = D_;
    constexpr size_t PS = (size_t)4096 * 1024;
    constexpr int LS = 4096 * 16;
    constexpr int TSZ = 128 * 64;
    __shared__ __bf16 sA[TSZ];
    __shared__ __bf16 sB[TSZ];

    const int tid = threadIdx.x, w = tid >> 6, l = tid & 63;
    const int lr = l & 15, lg = l >> 4;
    const int bm = blockIdx.y * 128, bn = blockIdx.x * 128;
    const int wm = w >> 1, wn = w & 1;

    // per-thread A-chunk geometry (fixed across k0)
    int arow[4], asl[4];
    #pragma unroll
    for (int c = 0; c < 4; ++c) {
        int q = w * 4 + c;
        int r = q * 8 + (l >> 3);
        arow[c] = r;                        // row within tile
        asl[c] = ((l & 7) ^ (r & 7)) * 8;   // swizzled col offset within 64
    }

    f32x4 acc[4][4] = {};

    for (int k0 = 0; k0 < K; k0 += 64) {
        const int h = k0 >> 6;
        __syncthreads();
        #pragma unroll
        for (int c = 0; c < 4; ++c) {
            int q = w * 4 + c;
            // B: async gload_lds as before
            int sl = asl[c];
            GLOAD16(Bt + (size_t)(bn + arow[c]) * K + k0 + sl, sB + q * 512);
            // A: fused combine (reg path)
            size_t off = (size_t)(bm + arow[c]) * D_ + k0 + sl;
            bf16x8 p0 = *(const bf16x8*)(P + off);
            bf16x8 p1 = *(const bf16x8*)(P + PS + off);
            float inv = 1.0f / (L[(bm + arow[c]) * 16 + h] + L[LS + (bm + arow[c]) * 16 + h]);
            bf16x8 a;
            #pragma unroll
            for (int j = 0; j < 8; ++j)
                a[j] = (__bf16)(((float)p0[j] + (float)p1[j]) * inv);
            *(bf16x8*)(sA + q * 512 + l * 8) = a;
        }
        __syncthreads();
        #pragma unroll
        for (int kk = 0; kk < 2; ++kk) {
            bf16x8 ah[4], bh[4];
            #pragma unroll
            for (int i = 0; i < 4; ++i) {
                int ra = wm * 64 + i * 16 + lr;
                int sa = ((kk * 4 + lg) ^ (ra & 7)) * 8;
                ah[i] = *(const bf16x8*)(sA + ra * 64 + sa);
                int rb = wn * 64 + i * 16 + lr;
                int sb = ((kk * 4 + lg) ^ (rb & 7)) * 8;
                bh[i] = *(const bf16x8*)(sB + rb * 64 + sb);
            }
            #pragma unroll
            for (int mi = 0; mi < 4; ++mi)
                #pragma unroll
                for (int ni = 0; ni < 4; ++ni)
                    acc[mi][ni] = __builtin_amdgcn_mfma_f32_16x16x32_bf16(ah[mi], bh[ni], acc[mi][ni], 0, 0, 0);
        }
    }

    #pragma unroll
    for (int ni = 0; ni < 4; ++ni) {
        int col = bn + wn * 64 + ni * 16 + lr;
        float bv = bias[col];
        #pragma unroll
        for (int mi = 0; mi < 4; ++mi) {
            #pragma unroll
            for (int r = 0; r < 4; ++r) {
                int row = bm + wm * 64 + mi * 16 + lg * 4 + r;
                C[(size_t)row * N + col] = acc[mi][ni][r] + bv;
            }
        }
    }
}

// ---------------- flash attention, 2-way split-KV, 2 q-frags/wave -----------
// (exact round-10 kernel: best measured config, attn = 55.6 us)
// grid 512: bid = ((qt*2 + kvh)*32) + (h*2+b)  [same head -> same XCD].
// 256 threads = 4 waves; wave owns 64 q rows (2 fragments of 32); block =
// 256 q rows, half the kv range (16 tiles of 64). Fixed-ref exp2 softmax.
// NOTE: do NOT declare launch_bounds(256,4) — unified VGPR+AGPR ~200/lane
// caps HW at 2 waves/SIMD; forcing 4 spilled 1.2GB to scratch (round 11).
__global__ __launch_bounds__(256, 2) void attn32_k(
    const __bf16* __restrict__ qkv, __bf16* __restrict__ Pout,
    float* __restrict__ Lout)
{
    __shared__ __bf16 Ks[2][64 * 64];   // [buf][k][d], XOR-swizzled
    __shared__ __bf16 Vt[2][64 * 64];   // [buf][d][k], XOR-swizzled

    const int tid = threadIdx.x, w = tid >> 6, l = tid & 63;
    const int q32 = l & 31, hi = l >> 5;
    const int bid = blockIdx.x;
    const int X = bid >> 5, hb = bid & 31;
    const int qt = X >> 1, kvh = X & 1;
    const int h = hb >> 1, b = hb & 1;
    const int q0 = qt * 256;
    const int kvbase = kvh * 1024;
    const size_t ldq = 3 * D_;
    const __bf16* Qg = qkv + (size_t)b * S_ * ldq + h * HD_;
    const __bf16* Kg = Qg + D_;
    const __bf16* Vg = Qg + 2 * D_;
    const int qg0 = q0 + w * 64 + q32;      // fragment 0 q-row; frag 1 = +32

    bf16x8 qf0[4], qf1[4];
    #pragma unroll
    for (int ds = 0; ds < 4; ++ds) {
        qf0[ds] = *(const bf16x8*)(Qg + (size_t)qg0 * ldq + ds * 16 + hi * 8);
        qf1[ds] = *(const bf16x8*)(Qg + (size_t)(qg0 + 32) * ldq + ds * 16 + hi * 8);
    }

    int krow[2], ksl[2], voff[2][8];
    const int vk = l;
    #pragma unroll
    for (int c = 0; c < 2; ++c) {
        int p = (w * 2 + c) * 64 + l;
        krow[c] = p >> 3;
        ksl[c]  = (p & 7) ^ (krow[c] & 7);
        int d0 = (w * 2 + c) * 8;
        #pragma unroll
        for (int j = 0; j < 8; ++j)
            voff[c][j] = (d0 + j) * 128 + (((vk >> 3) ^ j) * 16) + (vk & 7) * 2;
    }

    f32x16 o0[2] = {}, o1[2] = {};
    float lsum0 = 0.f, lsum1 = 0.f;
    bf16x8 vr[2];

    auto stageK = [&](int lt, int buf) {
        #pragma unroll
        for (int c = 0; c < 2; ++c)
            GLOAD16(Kg + (size_t)(kvbase + lt * 64 + krow[c]) * ldq + ksl[c] * 8,
                    &Ks[buf][(w * 2 + c) * 512]);
    };
    auto loadV = [&](int lt) {
        #pragma unroll
        for (int c = 0; c < 2; ++c)
            vr[c] = *(const bf16x8*)(Vg + (size_t)(kvbase + lt * 64 + vk) * ldq + (w * 2 + c) * 8);
    };
    auto writeV = [&](int buf) {
        #pragma unroll
        for (int c = 0; c < 2; ++c)
            #pragma unroll
            for (int j = 0; j < 8; ++j)
                *(__bf16*)((char*)&Vt[buf][0] + voff[c][j]) = vr[c][j];
    };

    auto smPack = [&](f32x16 sc[2], bf16x8 pa[2][2], float& ls) {
        float sum = 0.f;
        #pragma unroll
        for (int kb = 0; kb < 2; ++kb)
            #pragma unroll
            for (int i = 0; i < 16; ++i) {
                float pv = __builtin_amdgcn_exp2f(sc[kb][i]);
                sc[kb][i] = pv;
                sum += pv;
            }
        ls += sum;
        #pragma unroll
        for (int kb = 0; kb < 2; ++kb)
            #pragma unroll
            for (int tl = 0; tl < 2; ++tl) {
                int base = tl * 8;
                unsigned A0 = pack2(sc[kb][base + 0], sc[kb][base + 1]);
                unsigned A1 = pack2(sc[kb][base + 2], sc[kb][base + 3]);
                unsigned B0 = pack2(sc[kb][base + 4], sc[kb][base + 5]);
                unsigned B1 = pack2(sc[kb][base + 6], sc[kb][base + 7]);
                u32x2 s0 = __builtin_amdgcn_permlane32_swap(A0, B0, false, false);
                u32x2 s1 = __builtin_amdgcn_permlane32_swap(A1, B1, false, false);
                union { unsigned u[4]; bf16x8 v; } pu;
                pu.u[0] = s0[0]; pu.u[1] = s1[0]; pu.u[2] = s0[1]; pu.u[3] = s1[1];
                pa[kb][tl] = pu.v;
            }
    };

    auto computeTile = [&](int cur) {
        f32x16 sc0[2] = {}, sc1[2] = {};
        __builtin_amdgcn_s_setprio(1);
        #pragma unroll
        for (int kb = 0; kb < 2; ++kb) {
            int r = kb * 32 + q32;
            #pragma unroll
            for (int ds = 0; ds < 4; ++ds) {
                int slot = (ds * 2 + hi) ^ (r & 7);
                bf16x8 kf = *(const bf16x8*)((const char*)&Ks[cur][0] + r * 128 + slot * 16);
                sc0[kb] = __builtin_amdgcn_mfma_f32_32x32x16_bf16(kf, qf0[ds], sc0[kb], 0, 0, 0);
                sc1[kb] = __builtin_amdgcn_mfma_f32_32x32x16_bf16(kf, qf1[ds], sc1[kb], 0, 0, 0);
            }
        }
        __builtin_amdgcn_s_setprio(0);

        bf16x8 pa0[2][2], pa1[2][2];
        smPack(sc0, pa0, lsum0);
        smPack(sc1, pa1, lsum1);

        __builtin_amdgcn_s_setprio(1);
        #pragma unroll
        for (int db = 0; db < 2; ++db) {
            int dr = db * 32 + q32;
            #pragma unroll
            for (int tt = 0; tt < 4; ++tt) {
                int slot = (tt * 2 + hi) ^ (dr & 7);
                bf16x8 vf = *(const bf16x8*)((const char*)&Vt[cur][0] + dr * 128 + slot * 16);
                o0[db] = __builtin_amdgcn_mfma_f32_32x32x16_bf16(vf, pa0[tt >> 1][tt & 1], o0[db], 0, 0, 0);
                o1[db] = __builtin_amdgcn_mfma_f32_32x32x16_bf16(vf, pa1[tt >> 1][tt & 1], o1[db], 0, 0, 0);
            }
        }
        __builtin_amdgcn_s_setprio(0);
    };

    stageK(0, 0);
    loadV(0);
    writeV(0);
    __syncthreads();

    constexpr int NT = 16;   // 16 local tiles (half of kv range)
    for (int kt = 0; kt < NT; ++kt) {
        const int cur = kt & 1, nxt = cur ^ 1;
        if (kt < NT - 1) { stageK(kt + 1, nxt); loadV(kt + 1); }
        computeTile(cur);
        if (kt < NT - 1) writeV(nxt);
        __syncthreads();
    }

    lsum0 += __shfl_xor(lsum0, 32);
    lsum1 += __shfl_xor(lsum1, 32);
    const size_t orow0 = (size_t)b * S_ + qg0;
    __bf16* Pb0 = Pout + (size_t)kvh * (4096 * 1024) + orow0 * D_ + h * HD_;
    __bf16* Pb1 = Pb0 + (size_t)32 * D_;
    #pragma unroll
    for (int db = 0; db < 2; ++db)
        #pragma unroll
        for (int rg = 0; rg < 4; ++rg) {
            int d = db * 32 + 8 * rg + 4 * hi;
            bf16x4 ov0, ov1;
            #pragma unroll
            for (int i = 0; i < 4; ++i) {
                ov0[i] = (__bf16)o0[db][rg * 4 + i];
                ov1[i] = (__bf16)o1[db][rg * 4 + i];
            }
            *(bf16x4*)(Pb0 + d) = ov0;
            *(bf16x4*)(Pb1 + d) = ov1;
        }
    if (hi == 0) {
        Lout[(size_t)kvh * (4096 * 16) + orow0 * 16 + h] = lsum0;
        Lout[(size_t)kvh * (4096 * 16) + (orow0 + 32) * 16 + h] = lsum1;
    }
}

extern "C" void kernel_launch(void* const* d_in, const int* in_sizes, int n_in,
                              void* d_out, int out_size, void* d_ws, size_t ws_size,
                              hipStream_t stream) {
    const float* x     = (const float*)d_in[0];
    const float* Wqkv  = (const float*)d_in[1];
    const float* bqkv  = (const float*)d_in[2];
    const float* Wproj = (const float*)d_in[3];
    const float* bproj = (const float*)d_in[4];

    __bf16* ws = (__bf16*)d_ws;
    const size_t MB = 524288;            // bf16 elements per MB
    // layout (50.5 MB):
    //   wp_t   0-2    (live: prep -> GEMM2)
    //   qkv    2-26   (live: GEMM1 -> attn)
    //   x_bf  26-34, wq_t 34-40 (live: prep -> GEMM1)
    //   P     34-50   (2 x 8MB partials; overlays x_bf tail/wq_t after GEMM1)
    //   L     50-50.5
    __bf16* wp_t  = ws;
    __bf16* qkv   = ws + 2 * MB;
    __bf16* x_bf  = ws + 26 * MB;
    __bf16* wq_t  = ws + 34 * MB;
    __bf16* Pp    = ws + 34 * MB;        // overlays wq_t (dead after GEMM1)
    float*  Lp    = (float*)(ws + 50 * MB);

    const int M = B_ * S_;  // 4096

    // fused prep: x->bf16, Wqkv^T (q-scaled), Wproj^T
    prep_k<<<3072, 256, 0, stream>>>(x, x_bf, Wqkv, wq_t, Wproj, wp_t);

    // qkv = x @ W_qkv + b -> bf16 (q columns pre-scaled by QSCALE)
    gemm_nt_k<<<dim3(24, 32), 256, 0, stream>>>(
        x_bf, wq_t, bqkv, qkv, M, 3 * D_, D_, D_, QSCALE);

    // 2-way split-KV flash attention -> partials
    attn32_k<<<512, 256, 0, stream>>>(qkv, Pp, Lp);

    // out = ((P0+P1)/(l0+l1)) @ W_proj + b -> fp32 (combine fused into staging)
    gemm2_comb_k<<<dim3(8, 32), 256, 0, stream>>>(
        Pp, Lp, wp_t, bproj, (float*)d_out);
}

// Round 15
// 119.281 us; speedup vs baseline: 1.1532x; 1.1532x over previous
//
#include <hip/hip_runtime.h>
#include <math.h>

#define B_ 2
#define S_ 2048
#define D_ 1024
#define H_ 16
#define HD_ 64

typedef __bf16 bf16x8 __attribute__((ext_vector_type(8)));
typedef __bf16 bf16x4 __attribute__((ext_vector_type(4)));
typedef __bf16 bf16x2 __attribute__((ext_vector_type(2)));
typedef float f32x4 __attribute__((ext_vector_type(4)));
typedef float f32x16 __attribute__((ext_vector_type(16)));
typedef unsigned u32x2 __attribute__((ext_vector_type(2)));

#define GLOAD16(gsrc, ldst) \
  __builtin_amdgcn_global_load_lds((const __attribute__((address_space(1))) void*)(gsrc), \
                                   (__attribute__((address_space(3))) void*)(ldst), 16, 0, 0)

// 0.125 (1/sqrt(hd)) * log2(e), folded into W_qkv's q columns
#define QSCALE 0.18033688f

static __device__ __forceinline__ unsigned pack2(float a, float b) {
    bf16x2 v; v[0] = (__bf16)a; v[1] = (__bf16)b;
    return __builtin_bit_cast(unsigned, v);
}

// ---------------- fused prep: conv(x) + transpose(Wqkv) + transpose(Wproj) ---
// grid 3072: [0,2048) conv, [2048,2816) Wqkv transpose, [2816,3072) Wproj.
__global__ __launch_bounds__(256) void prep_k(
    const float* __restrict__ x, __bf16* __restrict__ x_bf,
    const float* __restrict__ Wqkv, __bf16* __restrict__ wq_t,
    const float* __restrict__ Wproj, __bf16* __restrict__ wp_t)
{
    __shared__ float t[64][65];
    const int tid = threadIdx.x;
    const int bid = blockIdx.x;

    if (bid < 2048) {
        int i = (bid * 256 + tid) * 8;
        float4 a = *(const float4*)(x + i);
        float4 b = *(const float4*)(x + i + 4);
        bf16x8 v;
        v[0] = (__bf16)a.x; v[1] = (__bf16)a.y; v[2] = (__bf16)a.z; v[3] = (__bf16)a.w;
        v[4] = (__bf16)b.x; v[5] = (__bf16)b.y; v[6] = (__bf16)b.z; v[7] = (__bf16)b.w;
        *(bf16x8*)(x_bf + i) = v;
        return;
    }

    const float* in; __bf16* outp; int K, N, qcols; float qs; int bx, by;
    if (bid < 2816) {
        int tt = bid - 2048; bx = tt % 48; by = tt / 48;
        in = Wqkv; outp = wq_t; K = D_; N = 3 * D_; qcols = D_; qs = QSCALE;
    } else {
        int tt = bid - 2816; bx = tt % 16; by = tt / 16;
        in = Wproj; outp = wp_t; K = D_; N = D_; qcols = 0; qs = 1.0f;
    }
    const int bj = bx * 64;   // N dim
    const int bi = by * 64;   // K dim
    #pragma unroll
    for (int it = 0; it < 4; ++it) {
        int idx = (tid + it * 256) * 4;
        int r = idx >> 6, c = idx & 63;
        float4 v = *(const float4*)(in + (size_t)(bi + r) * N + bj + c);
        t[r][c] = v.x; t[r][c+1] = v.y; t[r][c+2] = v.z; t[r][c+3] = v.w;
    }
    __syncthreads();
    int j = tid & 63;
    int i0 = (tid >> 6) * 16;
    float s = (bj + j) < qcols ? qs : 1.0f;
    bf16x8 h0, h1;
    #pragma unroll
    for (int ii = 0; ii < 8; ++ii) h0[ii] = (__bf16)(t[i0 + ii][j] * s);
    #pragma unroll
    for (int ii = 0; ii < 8; ++ii) h1[ii] = (__bf16)(t[i0 + 8 + ii][j] * s);
    size_t o = (size_t)(bj + j) * K + bi + i0;
    *(bf16x8*)(outp + o) = h0; *(bf16x8*)(outp + o + 8) = h1;
}

// ---------------- GEMM: C[M][N] = A[M][K] * Bt[N][K]^T + bias ----------------
// 1-D grid (XCD-swizzled, nwg%8==0), 128x128 tile, BK=64, 4 waves.
// bf16 output: coalesced epilogue via LDS re-staging (stride 128 = exactly
// the 32KB sA|sB region; re-read is linear -> bf16x8 streams).
// fp32 output: direct stores (64B segments, OK).
template<typename OutT>
__global__ __launch_bounds__(256) void gemm_nt_k(
    const __bf16* __restrict__ A, const __bf16* __restrict__ Bt,
    const float* __restrict__ bias, OutT* __restrict__ C,
    int M, int N, int K, int qcols, float qs)
{
    constexpr int TSZ = 128 * 64;
    constexpr bool BF16OUT = sizeof(OutT) == 2;
    __shared__ __bf16 smem[2 * TSZ];     // sA | sB; reused as C-tile in epilogue
    __bf16* sA = smem;
    __bf16* sB = smem + TSZ;

    const int tid = threadIdx.x, w = tid >> 6, l = tid & 63;
    const int lr = l & 15, lg = l >> 4;

    // XCD swizzle: consecutive logical tiles -> same XCD's L2
    const int nwg = gridDim.x;                 // multiple of 8
    const int bidl = blockIdx.x;
    const int swz = (bidl & 7) * (nwg >> 3) + (bidl >> 3);
    const int nbx = N >> 7;
    const int bx = swz % nbx, by = swz / nbx;
    const int bm = by * 128, bn = bx * 128;
    const int wm = w >> 1, wn = w & 1;

    f32x4 acc[4][4] = {};

    for (int k0 = 0; k0 < K; k0 += 64) {
        __syncthreads();
        #pragma unroll
        for (int c = 0; c < 4; ++c) {
            int q = w * 4 + c;
            int r = q * 8 + (l >> 3);
            int sl = ((l & 7) ^ (r & 7)) * 8;
            GLOAD16(A + (size_t)(bm + r) * K + k0 + sl, sA + q * 512);
            GLOAD16(Bt + (size_t)(bn + r) * K + k0 + sl, sB + q * 512);
        }
        __syncthreads();
        #pragma unroll
        for (int kk = 0; kk < 2; ++kk) {
            bf16x8 ah[4], bh[4];
            #pragma unroll
            for (int i = 0; i < 4; ++i) {
                int ra = wm * 64 + i * 16 + lr;
                int sa = ((kk * 4 + lg) ^ (ra & 7)) * 8;
                ah[i] = *(const bf16x8*)(sA + ra * 64 + sa);
                int rb = wn * 64 + i * 16 + lr;
                int sb = ((kk * 4 + lg) ^ (rb & 7)) * 8;
                bh[i] = *(const bf16x8*)(sB + rb * 64 + sb);
            }
            #pragma unroll
            for (int mi = 0; mi < 4; ++mi)
                #pragma unroll
                for (int ni = 0; ni < 4; ++ni)
                    acc[mi][ni] = __builtin_amdgcn_mfma_f32_16x16x32_bf16(ah[mi], bh[ni], acc[mi][ni], 0, 0, 0);
        }
    }

    if constexpr (BF16OUT) {
        // stage C-tile in LDS: [128 rows][128 cols], stride 128 (fills 32KB)
        __syncthreads();
        #pragma unroll
        for (int ni = 0; ni < 4; ++ni) {
            int col = wn * 64 + ni * 16 + lr;
            float bv = bias[bn + col];
            if (bn + col < qcols) bv *= qs;
            #pragma unroll
            for (int mi = 0; mi < 4; ++mi)
                #pragma unroll
                for (int r = 0; r < 4; ++r) {
                    int row = wm * 64 + mi * 16 + lg * 4 + r;
                    smem[row * 128 + col] = (__bf16)(acc[mi][ni][r] + bv);
                }
        }
        __syncthreads();
        #pragma unroll
        for (int p = 0; p < 8; ++p) {
            int idx = p * 2048 + tid * 8;        // linear over the 128x128 tile
            int row = idx >> 7;
            int col = idx & 127;
            bf16x8 v = *(const bf16x8*)(smem + idx);
            *(bf16x8*)((__bf16*)C + (size_t)(bm + row) * N + bn + col) = v;
        }
    } else {
        #pragma unroll
        for (int ni = 0; ni < 4; ++ni) {
            int col = bn + wn * 64 + ni * 16 + lr;
            float bv = bias[col];
            if (col < qcols) bv *= qs;
            #pragma unroll
            for (int mi = 0; mi < 4; ++mi) {
                #pragma unroll
                for (int r = 0; r < 4; ++r) {
                    int row = bm + wm * 64 + mi * 16 + lg * 4 + r;
                    float v = acc[mi][ni][r] + bv;
                    C[(size_t)row * N + col] = (OutT)v;
                }
            }
        }
    }
}

// ---------------- flash attention, 2-way split-KV, 2 q-frags/wave -----------
// (exact round-10 kernel: best measured config, attn = 55.6 us)
// grid 512: bid = ((qt*2 + kvh)*32) + (h*2+b)  [same head -> same XCD].
// 256 threads = 4 waves; wave owns 64 q rows (2 fragments of 32); block =
// 256 q rows, half the kv range (16 tiles of 64). Fixed-ref exp2 softmax.
// NOTE: do NOT declare launch_bounds(256,4) — unified VGPR+AGPR ~180/lane
// caps HW at 2 waves/SIMD; forcing 4 spilled 1.2GB to scratch (round 11).
__global__ __launch_bounds__(256, 2) void attn32_k(
    const __bf16* __restrict__ qkv, __bf16* __restrict__ Pout,
    float* __restrict__ Lout)
{
    __shared__ __bf16 Ks[2][64 * 64];   // [buf][k][d], XOR-swizzled
    __shared__ __bf16 Vt[2][64 * 64];   // [buf][d][k], XOR-swizzled

    const int tid = threadIdx.x, w = tid >> 6, l = tid & 63;
    const int q32 = l & 31, hi = l >> 5;
    const int bid = blockIdx.x;
    const int X = bid >> 5, hb = bid & 31;
    const int qt = X >> 1, kvh = X & 1;
    const int h = hb >> 1, b = hb & 1;
    const int q0 = qt * 256;
    const int kvbase = kvh * 1024;
    const size_t ldq = 3 * D_;
    const __bf16* Qg = qkv + (size_t)b * S_ * ldq + h * HD_;
    const __bf16* Kg = Qg + D_;
    const __bf16* Vg = Qg + 2 * D_;
    const int qg0 = q0 + w * 64 + q32;      // fragment 0 q-row; frag 1 = +32

    bf16x8 qf0[4], qf1[4];
    #pragma unroll
    for (int ds = 0; ds < 4; ++ds) {
        qf0[ds] = *(const bf16x8*)(Qg + (size_t)qg0 * ldq + ds * 16 + hi * 8);
        qf1[ds] = *(const bf16x8*)(Qg + (size_t)(qg0 + 32) * ldq + ds * 16 + hi * 8);
    }

    int krow[2], ksl[2], voff[2][8];
    const int vk = l;
    #pragma unroll
    for (int c = 0; c < 2; ++c) {
        int p = (w * 2 + c) * 64 + l;
        krow[c] = p >> 3;
        ksl[c]  = (p & 7) ^ (krow[c] & 7);
        int d0 = (w * 2 + c) * 8;
        #pragma unroll
        for (int j = 0; j < 8; ++j)
            voff[c][j] = (d0 + j) * 128 + (((vk >> 3) ^ j) * 16) + (vk & 7) * 2;
    }

    f32x16 o0[2] = {}, o1[2] = {};
    float lsum0 = 0.f, lsum1 = 0.f;
    bf16x8 vr[2];

    auto stageK = [&](int lt, int buf) {
        #pragma unroll
        for (int c = 0; c < 2; ++c)
            GLOAD16(Kg + (size_t)(kvbase + lt * 64 + krow[c]) * ldq + ksl[c] * 8,
                    &Ks[buf][(w * 2 + c) * 512]);
    };
    auto loadV = [&](int lt) {
        #pragma unroll
        for (int c = 0; c < 2; ++c)
            vr[c] = *(const bf16x8*)(Vg + (size_t)(kvbase + lt * 64 + vk) * ldq + (w * 2 + c) * 8);
    };
    auto writeV = [&](int buf) {
        #pragma unroll
        for (int c = 0; c < 2; ++c)
            #pragma unroll
            for (int j = 0; j < 8; ++j)
                *(__bf16*)((char*)&Vt[buf][0] + voff[c][j]) = vr[c][j];
    };

    auto smPack = [&](f32x16 sc[2], bf16x8 pa[2][2], float& ls) {
        float sum = 0.f;
        #pragma unroll
        for (int kb = 0; kb < 2; ++kb)
            #pragma unroll
            for (int i = 0; i < 16; ++i) {
                float pv = __builtin_amdgcn_exp2f(sc[kb][i]);
                sc[kb][i] = pv;
                sum += pv;
            }
        ls += sum;
        #pragma unroll
        for (int kb = 0; kb < 2; ++kb)
            #pragma unroll
            for (int tl = 0; tl < 2; ++tl) {
                int base = tl * 8;
                unsigned A0 = pack2(sc[kb][base + 0], sc[kb][base + 1]);
                unsigned A1 = pack2(sc[kb][base + 2], sc[kb][base + 3]);
                unsigned B0 = pack2(sc[kb][base + 4], sc[kb][base + 5]);
                unsigned B1 = pack2(sc[kb][base + 6], sc[kb][base + 7]);
                u32x2 s0 = __builtin_amdgcn_permlane32_swap(A0, B0, false, false);
                u32x2 s1 = __builtin_amdgcn_permlane32_swap(A1, B1, false, false);
                union { unsigned u[4]; bf16x8 v; } pu;
                pu.u[0] = s0[0]; pu.u[1] = s1[0]; pu.u[2] = s0[1]; pu.u[3] = s1[1];
                pa[kb][tl] = pu.v;
            }
    };

    auto computeTile = [&](int cur) {
        f32x16 sc0[2] = {}, sc1[2] = {};
        __builtin_amdgcn_s_setprio(1);
        #pragma unroll
        for (int kb = 0; kb < 2; ++kb) {
            int r = kb * 32 + q32;
            #pragma unroll
            for (int ds = 0; ds < 4; ++ds) {
                int slot = (ds * 2 + hi) ^ (r & 7);
                bf16x8 kf = *(const bf16x8*)((const char*)&Ks[cur][0] + r * 128 + slot * 16);
                sc0[kb] = __builtin_amdgcn_mfma_f32_32x32x16_bf16(kf, qf0[ds], sc0[kb], 0, 0, 0);
                sc1[kb] = __builtin_amdgcn_mfma_f32_32x32x16_bf16(kf, qf1[ds], sc1[kb], 0, 0, 0);
            }
        }
        __builtin_amdgcn_s_setprio(0);

        bf16x8 pa0[2][2], pa1[2][2];
        smPack(sc0, pa0, lsum0);
        smPack(sc1, pa1, lsum1);

        __builtin_amdgcn_s_setprio(1);
        #pragma unroll
        for (int db = 0; db < 2; ++db) {
            int dr = db * 32 + q32;
            #pragma unroll
            for (int tt = 0; tt < 4; ++tt) {
                int slot = (tt * 2 + hi) ^ (dr & 7);
                bf16x8 vf = *(const bf16x8*)((const char*)&Vt[cur][0] + dr * 128 + slot * 16);
                o0[db] = __builtin_amdgcn_mfma_f32_32x32x16_bf16(vf, pa0[tt >> 1][tt & 1], o0[db], 0, 0, 0);
                o1[db] = __builtin_amdgcn_mfma_f32_32x32x16_bf16(vf, pa1[tt >> 1][tt & 1], o1[db], 0, 0, 0);
            }
        }
        __builtin_amdgcn_s_setprio(0);
    };

    stageK(0, 0);
    loadV(0);
    writeV(0);
    __syncthreads();

    constexpr int NT = 16;   // 16 local tiles (half of kv range)
    for (int kt = 0; kt < NT; ++kt) {
        const int cur = kt & 1, nxt = cur ^ 1;
        if (kt < NT - 1) { stageK(kt + 1, nxt); loadV(kt + 1); }
        computeTile(cur);
        if (kt < NT - 1) writeV(nxt);
        __syncthreads();
    }

    lsum0 += __shfl_xor(lsum0, 32);
    lsum1 += __shfl_xor(lsum1, 32);
    const size_t orow0 = (size_t)b * S_ + qg0;
    __bf16* Pb0 = Pout + (size_t)kvh * (4096 * 1024) + orow0 * D_ + h * HD_;
    __bf16* Pb1 = Pb0 + (size_t)32 * D_;
    #pragma unroll
    for (int db = 0; db < 2; ++db)
        #pragma unroll
        for (int rg = 0; rg < 4; ++rg) {
            int d = db * 32 + 8 * rg + 4 * hi;
            bf16x4 ov0, ov1;
            #pragma unroll
            for (int i = 0; i < 4; ++i) {
                ov0[i] = (__bf16)o0[db][rg * 4 + i];
                ov1[i] = (__bf16)o1[db][rg * 4 + i];
            }
            *(bf16x4*)(Pb0 + d) = ov0;
            *(bf16x4*)(Pb1 + d) = ov1;
        }
    if (hi == 0) {
        Lout[(size_t)kvh * (4096 * 16) + orow0 * 16 + h] = lsum0;
        Lout[(size_t)kvh * (4096 * 16) + (orow0 + 32) * 16 + h] = lsum1;
    }
}

// ---------------- combine: attn = (P0 + P1) / (l0 + l1) -> bf16 -------------
__global__ __launch_bounds__(256) void combine_k(
    const __bf16* __restrict__ P, const float* __restrict__ L,
    __bf16* __restrict__ attnb)
{
    int i = (blockIdx.x * 256 + threadIdx.x) * 8;
    int row = i >> 10;            // b*S + q
    int h = (i & 1023) >> 6;
    float l0 = L[row * 16 + h];
    float l1 = L[4096 * 16 + row * 16 + h];
    float inv = 1.0f / (l0 + l1);
    bf16x8 p0 = *(const bf16x8*)(P + i);
    bf16x8 p1 = *(const bf16x8*)(P + 4096 * 1024 + i);
    bf16x8 r;
    #pragma unroll
    for (int j = 0; j < 8; ++j)
        r[j] = (__bf16)(((float)p0[j] + (float)p1[j]) * inv);
    *(bf16x8*)(attnb + i) = r;
}

extern "C" void kernel_launch(void* const* d_in, const int* in_sizes, int n_in,
                              void* d_out, int out_size, void* d_ws, size_t ws_size,
                              hipStream_t stream) {
    const float* x     = (const float*)d_in[0];
    const float* Wqkv  = (const float*)d_in[1];
    const float* bqkv  = (const float*)d_in[2];
    const float* Wproj = (const float*)d_in[3];
    const float* bproj = (const float*)d_in[4];

    __bf16* ws = (__bf16*)d_ws;
    const size_t MB = 524288;            // bf16 elements per MB
    // layout (50.5 MB):
    //   wp_t(2) | qkv(24) | attnb(8) | x_bf(8)+wq_t(6) -> P(16 overlay) | L(0.5)
    __bf16* wp_t  = ws;
    __bf16* qkv   = ws + 2 * MB;
    __bf16* attnb = ws + 26 * MB;
    __bf16* x_bf  = ws + 34 * MB;
    __bf16* wq_t  = ws + 42 * MB;
    __bf16* Pp    = ws + 34 * MB;        // overlays x_bf/wq_t (dead after GEMM1)
    float*  Lp    = (float*)(ws + 50 * MB);

    const int M = B_ * S_;  // 4096

    // fused prep: x->bf16, Wqkv^T (q-scaled), Wproj^T
    prep_k<<<3072, 256, 0, stream>>>(x, x_bf, Wqkv, wq_t, Wproj, wp_t);

    // qkv = x @ W_qkv + b -> bf16 (q columns pre-scaled by QSCALE)
    gemm_nt_k<__bf16><<<768, 256, 0, stream>>>(
        x_bf, wq_t, bqkv, qkv, M, 3 * D_, D_, D_, QSCALE);

    // 2-way split-KV flash attention -> partials
    attn32_k<<<512, 256, 0, stream>>>(qkv, Pp, Lp);

    // combine partial halves -> bf16 attn
    combine_k<<<2048, 256, 0, stream>>>(Pp, Lp, attnb);

    // out = attn @ W_proj + b -> fp32
    gemm_nt_k<float><<<256, 256, 0, stream>>>(
        attnb, wp_t, bproj, (float*)d_out, M, D_, D_, 0, 1.0f);
}